// Round 7
// baseline (214.212 us; speedup 1.0000x reference)
//
#include <hip/hip_runtime.h>
#include <utility>

// ConvQuad2D as ONE pure GEMM over packed-f16 pair-features.
// Pipe budget per CU (r12..r17): matrix ~310 cyc, LDS ~310 cyc, VALU ~250
// cyc per chunk-round; observed time ~= their SUM. Schedule changes that
// add register pressure regress (r14, r17); the kernel needs EXACTLY the
// 128-VGPR / 4-waves-per-EU point.
// r18 (B-frags via global): confounded — dropping sB from LDS made the
// backend target 8 waves/EU -> 64 VGPR -> ~200MB scratch traffic.
// r19 (amdgpu_waves_per_eu(4,4) pin): no data — container failed; the
// attribute was the only build novelty, so r20 drops it.
// r20 = r18 + the EMPIRICALLY PROVEN occupancy pin: launch_bounds(512,4)
// and a 50KB dummy LDS buffer (kept alive via escaping asm) so the LDS
// footprint (61.7KB/block -> 2 blocks/CU) reproduces r12..r17's regalloc
// environment (128 VGPR, 16 waves/CU). B stream: lane-coalesced
// global_load_dwordx4 of the 50KB L2-resident fragB (~411MB aggregate
// ~13.7 TB/s << 34.5 TB/s L2 ceiling), 3-deep rotating prefetch covers
// ~200cyc L2 latency. DS pipe keeps only patch reads (~350cyc/wave-tile).
// Feature order (prep owns matching weights): slot s in [0,196):
//   s<181: pair (i,g), g in [i>>1,12]: (p_i*p_{2g}, p_i*p_{2g+1});
//          weights: j==i -> Wq[d,i,i]; j>i -> Wq[d,i,j]+Wq[d,j,i]; else 0
//   s<194: linear t=s-181: (p_{2t},p_{2t+1}) w/ Klin[j,d,o] (j==25 -> 0); else pad.
// k-slot: chunk c=s>>2, lane q = channel d, e = feature-in-chunk.

typedef _Float16 half2 __attribute__((ext_vector_type(2)));
typedef _Float16 half4 __attribute__((ext_vector_type(4)));
typedef _Float16 half8 __attribute__((ext_vector_type(8)));
typedef float floatx4 __attribute__((ext_vector_type(4)));

#define BB 8
#define HH 250
#define WW 250
#define NF 16
#define NSLOT_PAIR 181
#define NSLOT_LIN  13
#define NCHUNK     49              // 49*4 = 196 half2 slots = 392 features/channel
#define NFRAG      (NCHUNK * 64)   // 3136 B-fragments = 50,176 B

#define TW 32                 // tile width  (pixels) = 2 col-groups of 16
#define TH 16                 // tile height = 8 waves x 2 rows
#define XW (TW + 4)           // 36 staged cols
#define XH (TH + 4)           // 20 staged rows
#define XSZ (XW * XH)         // 720 positions (720 % 32 == 16 -> 2-way banks)

#define NBLK     512          // persistent blocks (2/CU)
#define NTILE_W  8            // ceil(250/32)
#define NTILE_H  16           // ceil(250/16)
#define NTILES   (BB * NTILE_H * NTILE_W)   // 1024
#define NT       (NTILES / NBLK)            // 2 tiles per block

__host__ __device__ constexpr int slot_i(int s) {
    int i = 0, base = 0;
    while (base + (13 - (i >> 1)) <= s) { base += 13 - (i >> 1); ++i; }
    return i;
}
__host__ __device__ constexpr int slot_g(int s) {
    int i = 0, base = 0;
    while (base + (13 - (i >> 1)) <= s) { base += 13 - (i >> 1); ++i; }
    return (i >> 1) + (s - base);
}

// ---------- pre-pass: B fragments in MFMA lane order ----------
__global__ void prep_frags(const float* __restrict__ lin_w,   // (5,5,4,16)
                           const float* __restrict__ quad_w,  // (4,25,25,16)
                           _Float16* __restrict__ fragB) {
    const int c = blockIdx.x;       // 0..48
    const int lane = threadIdx.x;   // 0..63
    const int n = lane & 15;
    const int d = lane >> 4;
    half8 frag;
    #pragma unroll
    for (int e = 0; e < 8; ++e) {
        const int f = c * 8 + e;
        const int s = f >> 1, hf = f & 1;
        float v = 0.f;
        if (s < NSLOT_PAIR) {
            int i = 0, base = 0;
            while (base + (13 - (i >> 1)) <= s) { base += 13 - (i >> 1); ++i; }
            const int g = (i >> 1) + (s - base);
            const int j = 2 * g + hf;
            if (j == i)
                v = quad_w[((d * 25 + i) * 25 + i) * 16 + n];
            else if (j > i && j < 25)
                v = quad_w[((d * 25 + i) * 25 + j) * 16 + n]
                  + quad_w[((d * 25 + j) * 25 + i) * 16 + n];
        } else if (s < NSLOT_PAIR + NSLOT_LIN) {
            const int j = 2 * (s - NSLOT_PAIR) + hf;
            if (j < 25) v = lin_w[(j * 4 + d) * 16 + n];
        }
        frag[e] = (_Float16)v;
    }
    *(half8*)(fragB + (c * 64 + lane) * 8) = frag;
}

// ---------- packed helpers ----------
__device__ __forceinline__ uint32_t pkbits(float lo, float hi) {
    return __builtin_bit_cast(uint32_t, __builtin_amdgcn_cvt_pkrtz(lo, hi));
}
__device__ __forceinline__ half2 bc32(uint32_t u) {
    return __builtin_bit_cast(half2, u);
}

template<int S>
__device__ __forceinline__ half2 slotval(const half2 (&pd2)[13]) {
    if constexpr (S < NSLOT_PAIR) {
        constexpr int i = slot_i(S), g = slot_g(S);
        constexpr int ir = i >> 1, ih = i & 1;
        const half2 src = pd2[ir];
        const half2 bi = {src[ih], src[ih]};   // op_sel broadcast
        return bi * pd2[g];                    // v_pk_mul_f16
    } else if constexpr (S < NSLOT_PAIR + NSLOT_LIN) {
        return pd2[S - NSLOT_PAIR];
    } else {
        return half2{(_Float16)0.f, (_Float16)0.f};
    }
}

template<int C>
__device__ __forceinline__ half8 make_frag(const half2 (&pd2)[13]) {
    const half2 a0 = slotval<C * 4 + 0>(pd2);
    const half2 a1 = slotval<C * 4 + 1>(pd2);
    const half2 a2 = slotval<C * 4 + 2>(pd2);
    const half2 a3 = slotval<C * 4 + 3>(pd2);
    const half4 lo = __builtin_shufflevector(a0, a1, 0, 1, 2, 3);
    const half4 hi = __builtin_shufflevector(a2, a3, 0, 1, 2, 3);
    return __builtin_shufflevector(lo, hi, 0, 1, 2, 3, 4, 5, 6, 7);
}

// r15: setprio around MFMA cluster. r18/r20: B straight from global
// (L2-hot fragB), 3-deep rotating prefetch to cover ~200cyc L2 latency.
template<size_t... Cs>
__device__ __forceinline__ void gemm_all(
    const half2 (&p0)[13], const half2 (&p1)[13],
    const half2 (&p2)[13], const half2 (&p3)[13],
    const half8* __restrict__ Bg,            // fragB + lane (global, coalesced)
    floatx4& a0, floatx4& a1, floatx4& a2, floatx4& a3,
    std::index_sequence<Cs...>) {
    half8 bf0 = Bg[0 * 64];                  // chunk C fragment at Bg[C*64]
    half8 bf1 = Bg[1 * 64];
    half8 bf2 = Bg[2 * 64];
    (([&] {
        constexpr int C = (int)Cs;
        const half8 bf = bf0;                // frag for chunk C (issued at C-3)
        bf0 = bf1;
        bf1 = bf2;
        if constexpr (C + 3 < NCHUNK) bf2 = Bg[(C + 3) * 64];
        __builtin_amdgcn_s_setprio(1);
        a0 = __builtin_amdgcn_mfma_f32_16x16x32_f16(make_frag<C>(p0), bf, a0, 0, 0, 0);
        a1 = __builtin_amdgcn_mfma_f32_16x16x32_f16(make_frag<C>(p1), bf, a1, 0, 0, 0);
        a2 = __builtin_amdgcn_mfma_f32_16x16x32_f16(make_frag<C>(p2), bf, a2, 0, 0, 0);
        a3 = __builtin_amdgcn_mfma_f32_16x16x32_f16(make_frag<C>(p3), bf, a3, 0, 0, 0);
        __builtin_amdgcn_s_setprio(0);
    }()), ...);
}

// ---------- direct patch-slot reads from the f16-pair LDS image ----------
// base = xt2 + q*XSZ + r0*XW + m (+16 for col-group 1); row stride XW.
// pd[t] = half2(pf[2t], pf[2t+1]) with pf = row-major 5x5 patch + pad:
// 10 intra-row pair-words, 2 cross-row combines, 1 masked tail. All imm offs.
__device__ __forceinline__ void patches_direct(const uint32_t* base, half2 (&pd)[13]) {
    pd[0]  = bc32(base[0 * XW + 0]);
    pd[1]  = bc32(base[0 * XW + 2]);
    pd[3]  = bc32(base[1 * XW + 1]);
    pd[4]  = bc32(base[1 * XW + 3]);
    pd[5]  = bc32(base[2 * XW + 0]);
    pd[6]  = bc32(base[2 * XW + 2]);
    pd[8]  = bc32(base[3 * XW + 1]);
    pd[9]  = bc32(base[3 * XW + 3]);
    pd[10] = bc32(base[4 * XW + 0]);
    pd[11] = bc32(base[4 * XW + 2]);
    // cross-row pairs: (elem4, elem5) and (elem14, elem15); tail (elem24, 0)
    pd[2]  = bc32((base[0 * XW + 4] & 0xffffu) | (base[1 * XW + 0] << 16));
    pd[7]  = bc32((base[2 * XW + 4] & 0xffffu) | (base[3 * XW + 0] << 16));
    pd[12] = bc32(base[4 * XW + 4] & 0xffffu);
}

// ---------- tile index -> (b, h0, w0) ----------
__device__ __forceinline__ void tile_coords(int T, int& b, int& h0, int& w0) {
    b = T >> 7;                  // 128 tiles per batch image (8w x 16h)
    const int rem = T & 127;
    h0 = (rem >> 3) * TH;
    w0 = (rem & 7) * TW;
}

// ---------- x-halo prefetch into registers (2 positions/thread) ----------
__device__ __forceinline__ float4 halo_load(const float* __restrict__ x,
                                            int b, int h0, int w0, int p) {
    const int hh = p / XW, ww = p % XW;
    const int r = h0 + hh - 2, c = w0 + ww - 2;
    float4 v = make_float4(0.f, 0.f, 0.f, 0.f);
    if ((unsigned)r < (unsigned)HH && (unsigned)c < (unsigned)WW)
        v = ((const float4*)x)[(b * HH + r) * WW + c];
    return v;
}

__device__ __forceinline__ void xload_regs(const float* __restrict__ x,
                                           int b, int h0, int w0,
                                           float4& v0, float4& v1) {
    const int p0 = threadIdx.x;
    v0 = (p0 < XSZ) ? halo_load(x, b, h0, w0, p0) : make_float4(0.f, 0.f, 0.f, 0.f);
    const int p1 = p0 + 512;
    v1 = (p1 < XSZ) ? halo_load(x, b, h0, w0, p1) : make_float4(0.f, 0.f, 0.f, 0.f);
}

// ---------- pack + write the f16-pair image ----------
// Neighbor (col+1) value comes from lane+1 via shuffle; lane 63 re-loads it
// from global (L1-hot). Position ww=XW-1's hi half is never consumed.
__device__ __forceinline__ void xwrite_lds(uint32_t* xt2, float4 v0, float4 v1,
                                           const float* __restrict__ x,
                                           int b, int h0, int w0) {
    const int lane = threadIdx.x & 63;
    float4 v0n, v1n;
    v0n.x = __shfl(v0.x, lane + 1); v0n.y = __shfl(v0.y, lane + 1);
    v0n.z = __shfl(v0.z, lane + 1); v0n.w = __shfl(v0.w, lane + 1);
    v1n.x = __shfl(v1.x, lane + 1); v1n.y = __shfl(v1.y, lane + 1);
    v1n.z = __shfl(v1.z, lane + 1); v1n.w = __shfl(v1.w, lane + 1);
    const int p0 = threadIdx.x;
    const int p1 = p0 + 512;
    if (lane == 63) {                       // cross-wave neighbor fixup
        v0n = halo_load(x, b, h0, w0, p0 + 1);
        if (p1 + 1 < XSZ) v1n = halo_load(x, b, h0, w0, p1 + 1);
    }
    xt2[0 * XSZ + p0] = pkbits(v0.x, v0n.x);
    xt2[1 * XSZ + p0] = pkbits(v0.y, v0n.y);
    xt2[2 * XSZ + p0] = pkbits(v0.z, v0n.z);
    xt2[3 * XSZ + p0] = pkbits(v0.w, v0n.w);
    if (p1 < XSZ) {
        xt2[0 * XSZ + p1] = pkbits(v1.x, v1n.x);
        xt2[1 * XSZ + p1] = pkbits(v1.y, v1n.y);
        xt2[2 * XSZ + p1] = pkbits(v1.z, v1n.z);
        xt2[3 * XSZ + p1] = pkbits(v1.w, v1n.w);
    }
}

// ---------- main kernel: 512 persistent threads, 2 tiles per block ----------
// wave = 2 adjacent rows x 32 cols; segments: (r0,c0-15),(r0,c16-31),(r1,c0-15),(r1,c16-31)
// Occupancy pin (r20): launch_bounds(512,4) + 50KB dummy LDS keeps the
// total LDS at 61.7KB/block -> backend sees 2 blocks/CU max -> targets
// 4 waves/EU -> 128-VGPR budget (the regalloc point r12..r17 ran at).
__global__ __launch_bounds__(512, 4) void convquad_gemm(
    const float* __restrict__ x,       // (8,250,250,4)
    const float* __restrict__ bias,    // (16,)
    const _Float16* __restrict__ fragB,
    float* __restrict__ out)           // (8,250,250,16)
{
    __shared__ uint32_t xt2[4 * XSZ];                 // 11,520 B: f16-pair image
    __shared__ __align__(16) _Float16 occ_pad[NFRAG * 8];  // 50,176 B occupancy shaper

    const int lane = threadIdx.x & 63;
    const int wv = threadIdx.x >> 6;     // row-pair within tile
    const int m = lane & 15;             // pixel within 16-col segment; also o
    const int q = lane >> 4;             // channel for A; row-quad for D
    const float bo = bias[m];
    const half8* Bg = (const half8*)fragB + lane;   // lane-coalesced B stream

    // keep occ_pad alive (address escapes into asm -> no DCE); one dead
    // store per thread, zero steady-state cost.
    occ_pad[threadIdx.x] = (_Float16)0.f;
    asm volatile("" : : "v"(occ_pad + threadIdx.x) : "memory");

    // ---- prologue: prefetch x (tile 0), one barrier ----
    int b, h0, w0;
    tile_coords(blockIdx.x, b, h0, w0);
    float4 v0, v1;
    xload_regs(x, b, h0, w0, v0, v1);
    xwrite_lds(xt2, v0, v1, x, b, h0, w0);
    __syncthreads();

    #pragma unroll 1
    for (int t = 0; t < NT; ++t) {
        // prefetch next tile's x-halo into registers (latency hides under compute)
        int bn, h0n, w0n;
        if (t + 1 < NT) {
            tile_coords(blockIdx.x + (t + 1) * NBLK, bn, h0n, w0n);
            xload_regs(x, bn, h0n, w0n, v0, v1);
        }

        // ---- patches: direct pair-word reads, one base reg, imm offsets ----
        const uint32_t* pbase = xt2 + q * XSZ + (2 * wv) * XW + m;
        half2 pd0[13], pd1[13], pd2[13], pd3[13];
        patches_direct(pbase,           pd0);   // row r0,   cols m..
        patches_direct(pbase + 16,      pd1);   // row r0,   cols m+16..
        patches_direct(pbase + XW,      pd2);   // row r0+1, cols m..
        patches_direct(pbase + XW + 16, pd3);   // row r0+1, cols m+16..

        floatx4 acc0 = {bo, bo, bo, bo};
        floatx4 acc1 = acc0, acc2 = acc0, acc3 = acc0;
        gemm_all(pd0, pd1, pd2, pd3, Bg,
                 acc0, acc1, acc2, acc3, std::make_index_sequence<NCHUNK>{});

        // ---- store: seg0/1 -> row r0, seg2/3 -> row r1 ----
        const int r0 = h0 + 2 * wv;
        #pragma unroll
        for (int rr = 0; rr < 2; ++rr) {
            const int h = r0 + rr;
            if (h < HH) {
                const int rowbase = (b * HH + h) * WW;
                const floatx4& aA = rr ? acc2 : acc0;
                const floatx4& aB = rr ? acc3 : acc1;
                #pragma unroll
                for (int r = 0; r < 4; ++r) {
                    const int wA = w0 + q * 4 + r;
                    if (wA < WW) out[(rowbase + wA) * NF + m] = aA[r];
                    const int wB = w0 + 16 + q * 4 + r;
                    if (wB < WW) out[(rowbase + wB) * NF + m] = aB[r];
                }
            }
        }

        // ---- swap in next tile's x (cheap: regs->LDS + barriers) ----
        if (t + 1 < NT) {
            b = bn; h0 = h0n; w0 = w0n;
            __syncthreads();              // everyone done reading xt2
            xwrite_lds(xt2, v0, v1, x, b, h0, w0);
            __syncthreads();              // writes visible
        }
    }
}

extern "C" void kernel_launch(void* const* d_in, const int* in_sizes, int n_in,
                              void* d_out, int out_size, void* d_ws, size_t ws_size,
                              hipStream_t stream) {
    const float* x      = (const float*)d_in[0];
    const float* lin_w  = (const float*)d_in[1];
    const float* quad_w = (const float*)d_in[2];
    const float* bias   = (const float*)d_in[3];
    float* out = (float*)d_out;
    _Float16* fragB = (_Float16*)d_ws;   // 50,176 B

    prep_frags<<<dim3(NCHUNK), dim3(64), 0, stream>>>(lin_w, quad_w, fragB);

    convquad_gemm<<<dim3(NBLK), dim3(512), 0, stream>>>(x, bias, fragB, out);
}

// Round 8
// 172.361 us; speedup vs baseline: 1.2428x; 1.2428x over previous
//
#include <hip/hip_runtime.h>
#include <utility>

// ConvQuad2D as ONE pure GEMM over packed-f16 pair-features.
// Pipe budget per CU (r12..r17): matrix ~310 cyc, LDS ~310 cyc, VALU ~250
// cyc per chunk-round; observed time ~= their SUM. The kernel needs the
// 128-VGPR / 4-waves-per-EU regalloc point (r14/r17: +pressure spills;
// r18/r20: backend re-targets 8 waves/EU -> 64 VGPR -> ~200MB scratch).
// r20 PROVED the backend's VGPR targeting ignores the LDS-occupancy bound
// (61.9KB LDS pad, still 64 VGPR + spills). The ONLY pin is
// amdgpu_waves_per_eu(4,4) = exactly 4 waves/EU -> 128-VGPR budget.
// r19 (same idea) got no data (container acquire failure, attributed to
// infra); r21 reruns it clean: no occ_pad, B-frags streamed from global.
// B stream: lane-coalesced global_load_dwordx4 of the 50KB L2-resident
// fragB (~411MB aggregate ~ 13.7 TB/s << 34.5 TB/s L2 ceiling), 3-deep
// rotating prefetch covers ~200cyc L2 latency. DS pipe keeps only patch
// reads (~350cyc/wave-tile). LDS/block = 11.5KB.
// Pre-committed decision rule: clean+fast -> theory confirmed; clean+
// neutral -> r15 converged, revert & close; container fail or spills ->
// revert r15 & close.
// Feature order (prep owns matching weights): slot s in [0,196):
//   s<181: pair (i,g), g in [i>>1,12]: (p_i*p_{2g}, p_i*p_{2g+1});
//          weights: j==i -> Wq[d,i,i]; j>i -> Wq[d,i,j]+Wq[d,j,i]; else 0
//   s<194: linear t=s-181: (p_{2t},p_{2t+1}) w/ Klin[j,d,o] (j==25 -> 0); else pad.
// k-slot: chunk c=s>>2, lane q = channel d, e = feature-in-chunk.

typedef _Float16 half2 __attribute__((ext_vector_type(2)));
typedef _Float16 half4 __attribute__((ext_vector_type(4)));
typedef _Float16 half8 __attribute__((ext_vector_type(8)));
typedef float floatx4 __attribute__((ext_vector_type(4)));

#define BB 8
#define HH 250
#define WW 250
#define NF 16
#define NSLOT_PAIR 181
#define NSLOT_LIN  13
#define NCHUNK     49              // 49*4 = 196 half2 slots = 392 features/channel
#define NFRAG      (NCHUNK * 64)   // 3136 B-fragments = 50,176 B

#define TW 32                 // tile width  (pixels) = 2 col-groups of 16
#define TH 16                 // tile height = 8 waves x 2 rows
#define XW (TW + 4)           // 36 staged cols
#define XH (TH + 4)           // 20 staged rows
#define XSZ (XW * XH)         // 720 positions (720 % 32 == 16 -> 2-way banks)

#define NBLK     512          // persistent blocks (2/CU)
#define NTILE_W  8            // ceil(250/32)
#define NTILE_H  16           // ceil(250/16)
#define NTILES   (BB * NTILE_H * NTILE_W)   // 1024
#define NT       (NTILES / NBLK)            // 2 tiles per block

__host__ __device__ constexpr int slot_i(int s) {
    int i = 0, base = 0;
    while (base + (13 - (i >> 1)) <= s) { base += 13 - (i >> 1); ++i; }
    return i;
}
__host__ __device__ constexpr int slot_g(int s) {
    int i = 0, base = 0;
    while (base + (13 - (i >> 1)) <= s) { base += 13 - (i >> 1); ++i; }
    return (i >> 1) + (s - base);
}

// ---------- pre-pass: B fragments in MFMA lane order ----------
__global__ void prep_frags(const float* __restrict__ lin_w,   // (5,5,4,16)
                           const float* __restrict__ quad_w,  // (4,25,25,16)
                           _Float16* __restrict__ fragB) {
    const int c = blockIdx.x;       // 0..48
    const int lane = threadIdx.x;   // 0..63
    const int n = lane & 15;
    const int d = lane >> 4;
    half8 frag;
    #pragma unroll
    for (int e = 0; e < 8; ++e) {
        const int f = c * 8 + e;
        const int s = f >> 1, hf = f & 1;
        float v = 0.f;
        if (s < NSLOT_PAIR) {
            int i = 0, base = 0;
            while (base + (13 - (i >> 1)) <= s) { base += 13 - (i >> 1); ++i; }
            const int g = (i >> 1) + (s - base);
            const int j = 2 * g + hf;
            if (j == i)
                v = quad_w[((d * 25 + i) * 25 + i) * 16 + n];
            else if (j > i && j < 25)
                v = quad_w[((d * 25 + i) * 25 + j) * 16 + n]
                  + quad_w[((d * 25 + j) * 25 + i) * 16 + n];
        } else if (s < NSLOT_PAIR + NSLOT_LIN) {
            const int j = 2 * (s - NSLOT_PAIR) + hf;
            if (j < 25) v = lin_w[(j * 4 + d) * 16 + n];
        }
        frag[e] = (_Float16)v;
    }
    *(half8*)(fragB + (c * 64 + lane) * 8) = frag;
}

// ---------- packed helpers ----------
__device__ __forceinline__ uint32_t pkbits(float lo, float hi) {
    return __builtin_bit_cast(uint32_t, __builtin_amdgcn_cvt_pkrtz(lo, hi));
}
__device__ __forceinline__ half2 bc32(uint32_t u) {
    return __builtin_bit_cast(half2, u);
}

template<int S>
__device__ __forceinline__ half2 slotval(const half2 (&pd2)[13]) {
    if constexpr (S < NSLOT_PAIR) {
        constexpr int i = slot_i(S), g = slot_g(S);
        constexpr int ir = i >> 1, ih = i & 1;
        const half2 src = pd2[ir];
        const half2 bi = {src[ih], src[ih]};   // op_sel broadcast
        return bi * pd2[g];                    // v_pk_mul_f16
    } else if constexpr (S < NSLOT_PAIR + NSLOT_LIN) {
        return pd2[S - NSLOT_PAIR];
    } else {
        return half2{(_Float16)0.f, (_Float16)0.f};
    }
}

template<int C>
__device__ __forceinline__ half8 make_frag(const half2 (&pd2)[13]) {
    const half2 a0 = slotval<C * 4 + 0>(pd2);
    const half2 a1 = slotval<C * 4 + 1>(pd2);
    const half2 a2 = slotval<C * 4 + 2>(pd2);
    const half2 a3 = slotval<C * 4 + 3>(pd2);
    const half4 lo = __builtin_shufflevector(a0, a1, 0, 1, 2, 3);
    const half4 hi = __builtin_shufflevector(a2, a3, 0, 1, 2, 3);
    return __builtin_shufflevector(lo, hi, 0, 1, 2, 3, 4, 5, 6, 7);
}

// r15: setprio around MFMA cluster. r18/r21: B straight from global
// (L2-hot fragB), 3-deep rotating prefetch to cover ~200cyc L2 latency.
template<size_t... Cs>
__device__ __forceinline__ void gemm_all(
    const half2 (&p0)[13], const half2 (&p1)[13],
    const half2 (&p2)[13], const half2 (&p3)[13],
    const half8* __restrict__ Bg,            // fragB + lane (global, coalesced)
    floatx4& a0, floatx4& a1, floatx4& a2, floatx4& a3,
    std::index_sequence<Cs...>) {
    half8 bf0 = Bg[0 * 64];                  // chunk C fragment at Bg[C*64]
    half8 bf1 = Bg[1 * 64];
    half8 bf2 = Bg[2 * 64];
    (([&] {
        constexpr int C = (int)Cs;
        const half8 bf = bf0;                // frag for chunk C (issued at C-3)
        bf0 = bf1;
        bf1 = bf2;
        if constexpr (C + 3 < NCHUNK) bf2 = Bg[(C + 3) * 64];
        __builtin_amdgcn_s_setprio(1);
        a0 = __builtin_amdgcn_mfma_f32_16x16x32_f16(make_frag<C>(p0), bf, a0, 0, 0, 0);
        a1 = __builtin_amdgcn_mfma_f32_16x16x32_f16(make_frag<C>(p1), bf, a1, 0, 0, 0);
        a2 = __builtin_amdgcn_mfma_f32_16x16x32_f16(make_frag<C>(p2), bf, a2, 0, 0, 0);
        a3 = __builtin_amdgcn_mfma_f32_16x16x32_f16(make_frag<C>(p3), bf, a3, 0, 0, 0);
        __builtin_amdgcn_s_setprio(0);
    }()), ...);
}

// ---------- direct patch-slot reads from the f16-pair LDS image ----------
// base = xt2 + q*XSZ + r0*XW + m (+16 for col-group 1); row stride XW.
// pd[t] = half2(pf[2t], pf[2t+1]) with pf = row-major 5x5 patch + pad:
// 10 intra-row pair-words, 2 cross-row combines, 1 masked tail. All imm offs.
__device__ __forceinline__ void patches_direct(const uint32_t* base, half2 (&pd)[13]) {
    pd[0]  = bc32(base[0 * XW + 0]);
    pd[1]  = bc32(base[0 * XW + 2]);
    pd[3]  = bc32(base[1 * XW + 1]);
    pd[4]  = bc32(base[1 * XW + 3]);
    pd[5]  = bc32(base[2 * XW + 0]);
    pd[6]  = bc32(base[2 * XW + 2]);
    pd[8]  = bc32(base[3 * XW + 1]);
    pd[9]  = bc32(base[3 * XW + 3]);
    pd[10] = bc32(base[4 * XW + 0]);
    pd[11] = bc32(base[4 * XW + 2]);
    // cross-row pairs: (elem4, elem5) and (elem14, elem15); tail (elem24, 0)
    pd[2]  = bc32((base[0 * XW + 4] & 0xffffu) | (base[1 * XW + 0] << 16));
    pd[7]  = bc32((base[2 * XW + 4] & 0xffffu) | (base[3 * XW + 0] << 16));
    pd[12] = bc32(base[4 * XW + 4] & 0xffffu);
}

// ---------- tile index -> (b, h0, w0) ----------
__device__ __forceinline__ void tile_coords(int T, int& b, int& h0, int& w0) {
    b = T >> 7;                  // 128 tiles per batch image (8w x 16h)
    const int rem = T & 127;
    h0 = (rem >> 3) * TH;
    w0 = (rem & 7) * TW;
}

// ---------- x-halo prefetch into registers (2 positions/thread) ----------
__device__ __forceinline__ float4 halo_load(const float* __restrict__ x,
                                            int b, int h0, int w0, int p) {
    const int hh = p / XW, ww = p % XW;
    const int r = h0 + hh - 2, c = w0 + ww - 2;
    float4 v = make_float4(0.f, 0.f, 0.f, 0.f);
    if ((unsigned)r < (unsigned)HH && (unsigned)c < (unsigned)WW)
        v = ((const float4*)x)[(b * HH + r) * WW + c];
    return v;
}

__device__ __forceinline__ void xload_regs(const float* __restrict__ x,
                                           int b, int h0, int w0,
                                           float4& v0, float4& v1) {
    const int p0 = threadIdx.x;
    v0 = (p0 < XSZ) ? halo_load(x, b, h0, w0, p0) : make_float4(0.f, 0.f, 0.f, 0.f);
    const int p1 = p0 + 512;
    v1 = (p1 < XSZ) ? halo_load(x, b, h0, w0, p1) : make_float4(0.f, 0.f, 0.f, 0.f);
}

// ---------- pack + write the f16-pair image ----------
// Neighbor (col+1) value comes from lane+1 via shuffle; lane 63 re-loads it
// from global (L1-hot). Position ww=XW-1's hi half is never consumed.
__device__ __forceinline__ void xwrite_lds(uint32_t* xt2, float4 v0, float4 v1,
                                           const float* __restrict__ x,
                                           int b, int h0, int w0) {
    const int lane = threadIdx.x & 63;
    float4 v0n, v1n;
    v0n.x = __shfl(v0.x, lane + 1); v0n.y = __shfl(v0.y, lane + 1);
    v0n.z = __shfl(v0.z, lane + 1); v0n.w = __shfl(v0.w, lane + 1);
    v1n.x = __shfl(v1.x, lane + 1); v1n.y = __shfl(v1.y, lane + 1);
    v1n.z = __shfl(v1.z, lane + 1); v1n.w = __shfl(v1.w, lane + 1);
    const int p0 = threadIdx.x;
    const int p1 = p0 + 512;
    if (lane == 63) {                       // cross-wave neighbor fixup
        v0n = halo_load(x, b, h0, w0, p0 + 1);
        if (p1 + 1 < XSZ) v1n = halo_load(x, b, h0, w0, p1 + 1);
    }
    xt2[0 * XSZ + p0] = pkbits(v0.x, v0n.x);
    xt2[1 * XSZ + p0] = pkbits(v0.y, v0n.y);
    xt2[2 * XSZ + p0] = pkbits(v0.z, v0n.z);
    xt2[3 * XSZ + p0] = pkbits(v0.w, v0n.w);
    if (p1 < XSZ) {
        xt2[0 * XSZ + p1] = pkbits(v1.x, v1n.x);
        xt2[1 * XSZ + p1] = pkbits(v1.y, v1n.y);
        xt2[2 * XSZ + p1] = pkbits(v1.z, v1n.z);
        xt2[3 * XSZ + p1] = pkbits(v1.w, v1n.w);
    }
}

// ---------- main kernel: 512 persistent threads, 2 tiles per block ----------
// wave = 2 adjacent rows x 32 cols; segments: (r0,c0-15),(r0,c16-31),(r1,c0-15),(r1,c16-31)
// waves_per_eu(4,4): min=max=4 waves/EU -> backend MUST budget 512/4 = 128
// VGPR (r20 proved launch_bounds minimum + LDS footprint do NOT pin it).
__global__ __launch_bounds__(512)
__attribute__((amdgpu_waves_per_eu(4, 4))) void convquad_gemm(
    const float* __restrict__ x,       // (8,250,250,4)
    const float* __restrict__ bias,    // (16,)
    const _Float16* __restrict__ fragB,
    float* __restrict__ out)           // (8,250,250,16)
{
    __shared__ uint32_t xt2[4 * XSZ];                 // 11,520 B: f16-pair image

    const int lane = threadIdx.x & 63;
    const int wv = threadIdx.x >> 6;     // row-pair within tile
    const int m = lane & 15;             // pixel within 16-col segment; also o
    const int q = lane >> 4;             // channel for A; row-quad for D
    const float bo = bias[m];
    const half8* Bg = (const half8*)fragB + lane;   // lane-coalesced B stream

    // ---- prologue: prefetch x (tile 0), one barrier ----
    int b, h0, w0;
    tile_coords(blockIdx.x, b, h0, w0);
    float4 v0, v1;
    xload_regs(x, b, h0, w0, v0, v1);
    xwrite_lds(xt2, v0, v1, x, b, h0, w0);
    __syncthreads();

    #pragma unroll 1
    for (int t = 0; t < NT; ++t) {
        // prefetch next tile's x-halo into registers (latency hides under compute)
        int bn, h0n, w0n;
        if (t + 1 < NT) {
            tile_coords(blockIdx.x + (t + 1) * NBLK, bn, h0n, w0n);
            xload_regs(x, bn, h0n, w0n, v0, v1);
        }

        // ---- patches: direct pair-word reads, one base reg, imm offsets ----
        const uint32_t* pbase = xt2 + q * XSZ + (2 * wv) * XW + m;
        half2 pd0[13], pd1[13], pd2[13], pd3[13];
        patches_direct(pbase,           pd0);   // row r0,   cols m..
        patches_direct(pbase + 16,      pd1);   // row r0,   cols m+16..
        patches_direct(pbase + XW,      pd2);   // row r0+1, cols m..
        patches_direct(pbase + XW + 16, pd3);   // row r0+1, cols m+16..

        floatx4 acc0 = {bo, bo, bo, bo};
        floatx4 acc1 = acc0, acc2 = acc0, acc3 = acc0;
        gemm_all(pd0, pd1, pd2, pd3, Bg,
                 acc0, acc1, acc2, acc3, std::make_index_sequence<NCHUNK>{});

        // ---- store: seg0/1 -> row r0, seg2/3 -> row r1 ----
        const int r0 = h0 + 2 * wv;
        #pragma unroll
        for (int rr = 0; rr < 2; ++rr) {
            const int h = r0 + rr;
            if (h < HH) {
                const int rowbase = (b * HH + h) * WW;
                const floatx4& aA = rr ? acc2 : acc0;
                const floatx4& aB = rr ? acc3 : acc1;
                #pragma unroll
                for (int r = 0; r < 4; ++r) {
                    const int wA = w0 + q * 4 + r;
                    if (wA < WW) out[(rowbase + wA) * NF + m] = aA[r];
                    const int wB = w0 + 16 + q * 4 + r;
                    if (wB < WW) out[(rowbase + wB) * NF + m] = aB[r];
                }
            }
        }

        // ---- swap in next tile's x (cheap: regs->LDS + barriers) ----
        if (t + 1 < NT) {
            b = bn; h0 = h0n; w0 = w0n;
            __syncthreads();              // everyone done reading xt2
            xwrite_lds(xt2, v0, v1, x, b, h0, w0);
            __syncthreads();              // writes visible
        }
    }
}

extern "C" void kernel_launch(void* const* d_in, const int* in_sizes, int n_in,
                              void* d_out, int out_size, void* d_ws, size_t ws_size,
                              hipStream_t stream) {
    const float* x      = (const float*)d_in[0];
    const float* lin_w  = (const float*)d_in[1];
    const float* quad_w = (const float*)d_in[2];
    const float* bias   = (const float*)d_in[3];
    float* out = (float*)d_out;
    _Float16* fragB = (_Float16*)d_ws;   // 50,176 B

    prep_frags<<<dim3(NCHUNK), dim3(64), 0, stream>>>(lin_w, quad_w, fragB);

    convquad_gemm<<<dim3(NBLK), dim3(512), 0, stream>>>(x, bias, fragB, out);
}

// Round 9
// 98.557 us; speedup vs baseline: 2.1735x; 1.7488x over previous
//
#include <hip/hip_runtime.h>
#include <utility>

// ConvQuad2D as ONE pure GEMM over packed-f16 pair-features.
// CONVERGED FORM (r22 = r15 revert). Experiment matrix r13..r21:
//   r13 (DS -40%), r14 (b128 geometry), r16 (f16-pair image): throughput
//     cuts on DS/VALU -> neutral or regressed. Not throughput-bound.
//   r15 (2-deep B prefetch + setprio): -2.4us. Only positive lever.
//   r17 (A-frag pipeline): regressed — +8 VGPR live range at the 128-VGPR
//     wall spills.
//   r18/r20/r21 (B-frags from global, 3 occupancy-pin variants incl.
//     amdgpu_waves_per_eu(4,4)): backend re-targets 8 waves/EU -> 64-VGPR
//     budget -> ~200MB scratch spill. Unfixable at HIP source level.
// The kernel sits at a measured three-way balance: 128-VGPR regalloc,
// 61.7KB LDS (2 blocks/CU, 4 waves/EU), pipes MFMA~12.7 + VALU~9 + DS~15us
// serialized; every exit direction regresses.
// Feature order (prep owns matching weights): slot s in [0,196):
//   s<181: pair (i,g), g in [i>>1,12]: (p_i*p_{2g}, p_i*p_{2g+1});
//          weights: j==i -> Wq[d,i,i]; j>i -> Wq[d,i,j]+Wq[d,j,i]; else 0
//   s<194: linear t=s-181: (p_{2t},p_{2t+1}) w/ Klin[j,d,o] (j==25 -> 0); else pad.
// k-slot: chunk c=s>>2, lane q = channel d, e = feature-in-chunk.

typedef _Float16 half2 __attribute__((ext_vector_type(2)));
typedef _Float16 half4 __attribute__((ext_vector_type(4)));
typedef _Float16 half8 __attribute__((ext_vector_type(8)));
typedef float floatx4 __attribute__((ext_vector_type(4)));

#define BB 8
#define HH 250
#define WW 250
#define NF 16
#define NSLOT_PAIR 181
#define NSLOT_LIN  13
#define NCHUNK     49              // 49*4 = 196 half2 slots = 392 features/channel
#define NFRAG      (NCHUNK * 64)   // 3136 B-fragments = 50,176 B

#define TW 32                 // tile width  (pixels) = 2 col-groups of 16
#define TH 16                 // tile height = 8 waves x 2 rows
#define XW (TW + 4)           // 36 staged cols
#define XH (TH + 4)           // 20 staged rows
#define XSZ (XW * XH)         // 720 positions

#define NBLK     512          // persistent blocks (2/CU)
#define NTILE_W  8            // ceil(250/32)
#define NTILE_H  16           // ceil(250/16)
#define NTILES   (BB * NTILE_H * NTILE_W)   // 1024
#define NT       (NTILES / NBLK)            // 2 tiles per block

__host__ __device__ constexpr int slot_i(int s) {
    int i = 0, base = 0;
    while (base + (13 - (i >> 1)) <= s) { base += 13 - (i >> 1); ++i; }
    return i;
}
__host__ __device__ constexpr int slot_g(int s) {
    int i = 0, base = 0;
    while (base + (13 - (i >> 1)) <= s) { base += 13 - (i >> 1); ++i; }
    return (i >> 1) + (s - base);
}

// ---------- pre-pass: B fragments in MFMA lane order ----------
__global__ void prep_frags(const float* __restrict__ lin_w,   // (5,5,4,16)
                           const float* __restrict__ quad_w,  // (4,25,25,16)
                           _Float16* __restrict__ fragB) {
    const int c = blockIdx.x;       // 0..48
    const int lane = threadIdx.x;   // 0..63
    const int n = lane & 15;
    const int d = lane >> 4;
    half8 frag;
    #pragma unroll
    for (int e = 0; e < 8; ++e) {
        const int f = c * 8 + e;
        const int s = f >> 1, hf = f & 1;
        float v = 0.f;
        if (s < NSLOT_PAIR) {
            int i = 0, base = 0;
            while (base + (13 - (i >> 1)) <= s) { base += 13 - (i >> 1); ++i; }
            const int g = (i >> 1) + (s - base);
            const int j = 2 * g + hf;
            if (j == i)
                v = quad_w[((d * 25 + i) * 25 + i) * 16 + n];
            else if (j > i && j < 25)
                v = quad_w[((d * 25 + i) * 25 + j) * 16 + n]
                  + quad_w[((d * 25 + j) * 25 + i) * 16 + n];
        } else if (s < NSLOT_PAIR + NSLOT_LIN) {
            const int j = 2 * (s - NSLOT_PAIR) + hf;
            if (j < 25) v = lin_w[(j * 4 + d) * 16 + n];
        }
        frag[e] = (_Float16)v;
    }
    *(half8*)(fragB + (c * 64 + lane) * 8) = frag;
}

// ---------- packed helpers ----------
__device__ __forceinline__ half2 pk(float lo, float hi) {
    return __builtin_bit_cast(half2, __builtin_amdgcn_cvt_pkrtz(lo, hi));
}

template<int S>
__device__ __forceinline__ half2 slotval(const half2 (&pd2)[13]) {
    if constexpr (S < NSLOT_PAIR) {
        constexpr int i = slot_i(S), g = slot_g(S);
        constexpr int ir = i >> 1, ih = i & 1;
        const half2 src = pd2[ir];
        const half2 bi = {src[ih], src[ih]};   // op_sel broadcast
        return bi * pd2[g];                    // v_pk_mul_f16
    } else if constexpr (S < NSLOT_PAIR + NSLOT_LIN) {
        return pd2[S - NSLOT_PAIR];
    } else {
        return half2{(_Float16)0.f, (_Float16)0.f};
    }
}

template<int C>
__device__ __forceinline__ half8 make_frag(const half2 (&pd2)[13]) {
    const half2 a0 = slotval<C * 4 + 0>(pd2);
    const half2 a1 = slotval<C * 4 + 1>(pd2);
    const half2 a2 = slotval<C * 4 + 2>(pd2);
    const half2 a3 = slotval<C * 4 + 3>(pd2);
    const half4 lo = __builtin_shufflevector(a0, a1, 0, 1, 2, 3);
    const half4 hi = __builtin_shufflevector(a2, a3, 0, 1, 2, 3);
    return __builtin_shufflevector(lo, hi, 0, 1, 2, 3, 4, 5, 6, 7);
}

// r15: explicit 2-deep rotating B prefetch + setprio around MFMA cluster.
template<size_t... Cs>
__device__ __forceinline__ void gemm_all(
    const half2 (&p0)[13], const half2 (&p1)[13],
    const half2 (&p2)[13], const half2 (&p3)[13],
    const _Float16* sBlane,
    floatx4& a0, floatx4& a1, floatx4& a2, floatx4& a3,
    std::index_sequence<Cs...>) {
    const half8* B = (const half8*)sBlane;   // frag C at B[C*64] (imm offs C*1024B)
    half8 bf0 = B[0 * 64];
    half8 bf1 = B[1 * 64];
    (([&] {
        constexpr int C = (int)Cs;
        const half8 bf = bf0;                // frag for chunk C (issued at C-2)
        bf0 = bf1;
        if constexpr (C + 2 < NCHUNK) bf1 = B[(C + 2) * 64];
        __builtin_amdgcn_s_setprio(1);
        a0 = __builtin_amdgcn_mfma_f32_16x16x32_f16(make_frag<C>(p0), bf, a0, 0, 0, 0);
        a1 = __builtin_amdgcn_mfma_f32_16x16x32_f16(make_frag<C>(p1), bf, a1, 0, 0, 0);
        a2 = __builtin_amdgcn_mfma_f32_16x16x32_f16(make_frag<C>(p2), bf, a2, 0, 0, 0);
        a3 = __builtin_amdgcn_mfma_f32_16x16x32_f16(make_frag<C>(p3), bf, a3, 0, 0, 0);
        __builtin_amdgcn_s_setprio(0);
    }()), ...);
}

// ---------- 6x5 tap window -> two row-patches (vertical reuse) ----------
__device__ __forceinline__ void patches_from_window(const float* xt, int base,
                                                    half2 (&pdT)[13], half2 (&pdB)[13]) {
    float t6[6][5];
    #pragma unroll
    for (int rr = 0; rr < 6; ++rr)
        #pragma unroll
        for (int cc = 0; cc < 5; ++cc)
            t6[rr][cc] = xt[base + rr * XW + cc];

    float pf0[26], pf1[26];
    pf0[25] = 0.f; pf1[25] = 0.f;
    #pragma unroll
    for (int rr = 0; rr < 5; ++rr)
        #pragma unroll
        for (int cc = 0; cc < 5; ++cc) {
            pf0[rr * 5 + cc] = t6[rr][cc];       // pixel at row r0
            pf1[rr * 5 + cc] = t6[rr + 1][cc];   // pixel at row r0+1
        }
    #pragma unroll
    for (int t = 0; t < 13; ++t) {
        pdT[t] = pk(pf0[2 * t], pf0[2 * t + 1]);
        pdB[t] = pk(pf1[2 * t], pf1[2 * t + 1]);
    }
}

// ---------- tile index -> (b, h0, w0) ----------
__device__ __forceinline__ void tile_coords(int T, int& b, int& h0, int& w0) {
    b = T >> 7;                  // 128 tiles per batch image (8w x 16h)
    const int rem = T & 127;
    h0 = (rem >> 3) * TH;
    w0 = (rem & 7) * TW;
}

// ---------- x-halo prefetch into registers (2 positions/thread) ----------
__device__ __forceinline__ void xload_regs(const float* __restrict__ x,
                                           int b, int h0, int w0,
                                           float4& v0, float4& v1) {
    const int p0 = threadIdx.x;
    {
        const int hh = p0 / XW, ww = p0 % XW;
        const int r = h0 + hh - 2, c = w0 + ww - 2;
        v0 = make_float4(0.f, 0.f, 0.f, 0.f);
        if (p0 < XSZ && (unsigned)r < (unsigned)HH && (unsigned)c < (unsigned)WW)
            v0 = ((const float4*)x)[(b * HH + r) * WW + c];
    }
    const int p1 = p0 + 512;
    v1 = make_float4(0.f, 0.f, 0.f, 0.f);
    if (p1 < XSZ) {
        const int hh = p1 / XW, ww = p1 % XW;
        const int r = h0 + hh - 2, c = w0 + ww - 2;
        if ((unsigned)r < (unsigned)HH && (unsigned)c < (unsigned)WW)
            v1 = ((const float4*)x)[(b * HH + r) * WW + c];
    }
}

__device__ __forceinline__ void xwrite_lds(float* xt, const float4& v0, const float4& v1) {
    const int p0 = threadIdx.x;
    if (p0 < XSZ) {
        xt[0 * XSZ + p0] = v0.x;
        xt[1 * XSZ + p0] = v0.y;
        xt[2 * XSZ + p0] = v0.z;
        xt[3 * XSZ + p0] = v0.w;
    }
    const int p1 = p0 + 512;
    if (p1 < XSZ) {
        xt[0 * XSZ + p1] = v1.x;
        xt[1 * XSZ + p1] = v1.y;
        xt[2 * XSZ + p1] = v1.z;
        xt[3 * XSZ + p1] = v1.w;
    }
}

// ---------- main kernel: 512 persistent threads, 2 tiles per block ----------
// wave = 2 adjacent rows x 32 cols; segments: (r0,c0-15),(r0,c16-31),(r1,c0-15),(r1,c16-31)
__global__ __launch_bounds__(512, 4) void convquad_gemm(
    const float* __restrict__ x,       // (8,250,250,4)
    const float* __restrict__ bias,    // (16,)
    const _Float16* __restrict__ fragB,
    float* __restrict__ out)           // (8,250,250,16)
{
    __shared__ float xt[4 * XSZ];                     // 11,520 B: [c][hh][ww]
    __shared__ __align__(16) _Float16 sB[NFRAG * 8];  // 50,176 B

    const int lane = threadIdx.x & 63;
    const int wv = threadIdx.x >> 6;     // row-pair within tile
    const int m = lane & 15;             // pixel within 16-col segment; also o
    const int q = lane >> 4;             // channel for A; row-quad for D
    const float bo = bias[m];

    // ---- prologue: prefetch x (tile 0) + copy B, one barrier ----
    int b, h0, w0;
    tile_coords(blockIdx.x, b, h0, w0);
    float4 v0, v1;
    xload_regs(x, b, h0, w0, v0, v1);

    {   // coalesced 50KB B copy: global (L2-hot) -> LDS
        const float4* src = (const float4*)fragB;
        float4* dst = (float4*)sB;
        #pragma unroll
        for (int t = threadIdx.x; t < NFRAG * 8 / 8; t += 512) dst[t] = src[t];
    }
    xwrite_lds(xt, v0, v1);
    __syncthreads();

    #pragma unroll 1
    for (int t = 0; t < NT; ++t) {
        // prefetch next tile's x-halo into registers (latency hides under compute)
        int bn, h0n, w0n;
        if (t + 1 < NT) {
            tile_coords(blockIdx.x + (t + 1) * NBLK, bn, h0n, w0n);
            xload_regs(x, bn, h0n, w0n, v0, v1);
        }

        // ---- patches: 6x5 window per col-group serves both rows ----
        const int base = q * XSZ + (2 * wv) * XW + m;
        half2 pd0[13], pd1[13], pd2[13], pd3[13];
        patches_from_window(xt, base,      pd0, pd2);   // col-group 0: rows r0, r1
        patches_from_window(xt, base + 16, pd1, pd3);   // col-group 1: rows r0, r1

        floatx4 acc0 = {bo, bo, bo, bo};
        floatx4 acc1 = acc0, acc2 = acc0, acc3 = acc0;
        gemm_all(pd0, pd1, pd2, pd3, sB + lane * 8,
                 acc0, acc1, acc2, acc3, std::make_index_sequence<NCHUNK>{});

        // ---- store: seg0/1 -> row r0, seg2/3 -> row r1 ----
        const int r0 = h0 + 2 * wv;
        #pragma unroll
        for (int rr = 0; rr < 2; ++rr) {
            const int h = r0 + rr;
            if (h < HH) {
                const int rowbase = (b * HH + h) * WW;
                const floatx4& aA = rr ? acc2 : acc0;
                const floatx4& aB = rr ? acc3 : acc1;
                #pragma unroll
                for (int r = 0; r < 4; ++r) {
                    const int wA = w0 + q * 4 + r;
                    if (wA < WW) out[(rowbase + wA) * NF + m] = aA[r];
                    const int wB = w0 + 16 + q * 4 + r;
                    if (wB < WW) out[(rowbase + wB) * NF + m] = aB[r];
                }
            }
        }

        // ---- swap in next tile's x (cheap: regs->LDS + barriers) ----
        if (t + 1 < NT) {
            b = bn; h0 = h0n; w0 = w0n;
            __syncthreads();              // everyone done reading xt
            xwrite_lds(xt, v0, v1);
            __syncthreads();              // writes visible
        }
    }
}

extern "C" void kernel_launch(void* const* d_in, const int* in_sizes, int n_in,
                              void* d_out, int out_size, void* d_ws, size_t ws_size,
                              hipStream_t stream) {
    const float* x      = (const float*)d_in[0];
    const float* lin_w  = (const float*)d_in[1];
    const float* quad_w = (const float*)d_in[2];
    const float* bias   = (const float*)d_in[3];
    float* out = (float*)d_out;
    _Float16* fragB = (_Float16*)d_ws;   // 50,176 B

    prep_frags<<<dim3(NCHUNK), dim3(64), 0, stream>>>(lin_w, quad_w, fragB);

    convquad_gemm<<<dim3(NBLK), dim3(512), 0, stream>>>(x, bias, fragB, out);
}